// Round 7
// baseline (792.524 us; speedup 1.0000x reference)
//
#include <hip/hip_runtime.h>
#include <cstdint>

using u16 = unsigned short;
using u32 = unsigned int;

typedef _Float16 h8 __attribute__((ext_vector_type(8)));
typedef _Float16 h4 __attribute__((ext_vector_type(4)));
typedef _Float16 h2 __attribute__((ext_vector_type(2)));
typedef float f32x4 __attribute__((ext_vector_type(4)));

#define N_PER_B 175
#define NN 22400
#define HALF_N 11200
#define DCOL 1024

// async global->LDS, 16B per lane; LDS dst is wave-uniform base + lane*16
__device__ __forceinline__ void gload16(const void* g, void* l) {
  void* gnc = const_cast<void*>(g);
  __builtin_amdgcn_global_load_lds(
      (__attribute__((address_space(1))) unsigned int*)gnc,
      (__attribute__((address_space(3))) unsigned int*)l, 16, 0, 0);
}

// ---------------- degree / CSR build (bucketed by (dst, src-half)) ----------------

__global__ void degree_k(const int* __restrict__ es, const int* __restrict__ ed,
                         u32* __restrict__ dout, u32* __restrict__ din2, int nE) {
  int e = blockIdx.x * 256 + threadIdx.x;
  if (e < nE) {
    int s = es[e], d = ed[e];
    atomicAdd(&dout[s], 1u);
    atomicAdd(&din2[2 * d + (s >= HALF_N)], 1u);
  }
}

__global__ void dinv_k(const u32* __restrict__ dout, const u32* __restrict__ din2,
                       float* __restrict__ vo, float* __restrict__ vi) {
  int i = blockIdx.x * 256 + threadIdx.x;
  if (i < NN) {
    u32 a = dout[i]; if (a == 0u) a = 1u;
    u32 b = din2[2 * i] + din2[2 * i + 1]; if (b == 0u) b = 1u;
    vo[i] = rsqrtf((float)a);
    vi[i] = rsqrtf((float)b);
  }
}

// single-block scan, wave-shuffle based: 2 barriers per 1024-chunk
__global__ __launch_bounds__(1024) void scan_k(const u32* __restrict__ deg,
                                               u32* __restrict__ off, int n) {
  __shared__ u32 wsum[16];
  __shared__ u32 carry_s;
  int tid = threadIdx.x;
  int lane = tid & 63, w = tid >> 6;
  if (tid == 0) carry_s = 0u;
  __syncthreads();
  for (int base = 0; base < n; base += 1024) {
    u32 cb = carry_s;
    int i = base + tid;
    u32 v = (i < n) ? deg[i] : 0u;
    u32 x = v;
#pragma unroll
    for (int o = 1; o < 64; o <<= 1) {
      u32 t = __shfl_up(x, o);
      if (lane >= o) x += t;
    }
    if (lane == 63) wsum[w] = x;
    __syncthreads();
    u32 woff = 0;
#pragma unroll
    for (int j = 0; j < 16; ++j) { u32 s = wsum[j]; if (j < w) woff += s; }
    u32 incl = cb + woff + x;
    if (i < n) off[i] = incl - v;          // exclusive
    if (tid == 1023) carry_s = incl;
    __syncthreads();
  }
  if (tid == 0) off[n] = carry_s;
}

__global__ void scatter_k(const int* __restrict__ es, const int* __restrict__ ed,
                          const u32* __restrict__ off, u32* __restrict__ cur,
                          int* __restrict__ csr, int nE) {
  int e = blockIdx.x * 256 + threadIdx.x;
  if (e < nE) {
    int s = es[e];
    int seg = 2 * ed[e] + (s >= HALF_N);
    u32 p = atomicAdd(&cur[seg], 1u);
    csr[off[seg] + p] = s;
  }
}

// ---------------- concat + layernorm (+ *dvo) -> fp16 node matrix ----------------

__global__ __launch_bounds__(256) void ln_k(const float* __restrict__ mh,
    const float* __restrict__ eh, const float* __restrict__ sh,
    const float* __restrict__ te, const float* __restrict__ sc,
    const float* __restrict__ bi, const float* __restrict__ dvo,
    _Float16* __restrict__ x0) {
  int node = blockIdx.x;
  int b = node / N_PER_B;
  int p = node - b * N_PER_B;
  const float* row;
  int t;
  if (p < 100)      { row = mh + ((size_t)b * 100 + p) * 768;        t = 0; }
  else if (p < 150) { row = eh + ((size_t)b * 50 + (p - 100)) * 768; t = 1; }
  else              { row = sh + ((size_t)b * 25 + (p - 150)) * 768; t = 2; }
  int tid = threadIdx.x;
  const float* lp = (tid < 192) ? (row + tid * 4) : (te + t * 256 + (tid - 192) * 4);
  float4 v = *(const float4*)lp;
  float s = v.x + v.y + v.z + v.w;
  float q = v.x * v.x + v.y * v.y + v.z * v.z + v.w * v.w;
#pragma unroll
  for (int o = 32; o > 0; o >>= 1) { s += __shfl_down(s, o); q += __shfl_down(q, o); }
  __shared__ float red[8];
  int w = tid >> 6;
  if ((tid & 63) == 0) { red[w] = s; red[4 + w] = q; }
  __syncthreads();
  float ts = red[0] + red[1] + red[2] + red[3];
  float tq = red[4] + red[5] + red[6] + red[7];
  float mu = ts * (1.0f / 1024.0f);
  float var = tq * (1.0f / 1024.0f) - mu * mu;
  float r = rsqrtf(var + 1e-5f);
  float scale_o = dvo[node];
  int c = tid * 4;
  float4 g  = *(const float4*)(sc + c);
  float4 hb = *(const float4*)(bi + c);
  h4 o;
  o.x = (_Float16)(((v.x - mu) * r * g.x + hb.x) * scale_o);
  o.y = (_Float16)(((v.y - mu) * r * g.y + hb.y) * scale_o);
  o.z = (_Float16)(((v.z - mu) * r * g.z + hb.z) * scale_o);
  o.w = (_Float16)(((v.w - mu) * r * g.w + hb.w) * scale_o);
  *(h4*)(x0 + (size_t)node * DCOL + c) = o;
}

// ---------------- weight transpose fp32 [K][N] -> fp16 [N][K] ----------------

__global__ __launch_bounds__(256) void transpose_k(const float* __restrict__ W,
    _Float16* __restrict__ Wt, int K, int N) {
  __shared__ float tile[32][33];
  int n0 = blockIdx.x * 32, k0 = blockIdx.y * 32;
  int tx = threadIdx.x & 31, ty = threadIdx.x >> 5;  // 32 x 8
#pragma unroll
  for (int i = 0; i < 32; i += 8)
    tile[ty + i][tx] = W[(size_t)(k0 + ty + i) * N + n0 + tx];
  __syncthreads();
#pragma unroll
  for (int i = 0; i < 32; i += 8)
    Wt[(size_t)(n0 + ty + i) * K + k0 + tx] = (_Float16)tile[tx][ty + i];
}

// ---------------- CSR aggregation, src-partitioned two-pass ----------------
// xs is pre-scaled by dvo. One wave per (dst, 128-col chunk); lane = col pair.
// PASS 0: sum over srcs < HALF_N  -> fp16 partial in agg
// PASS 1: sum over srcs >= HALF_N + partial, * dvi -> agg
// Per-(chunk,pass) random working set = 11200*256B = 2.87MB < 4MB L2/XCD.

template<int ENT, int PASS>
__global__ __launch_bounds__(256) void aggregate_k(const _Float16* __restrict__ xs,
    const u32* __restrict__ off, const int* __restrict__ srcs,
    const float* __restrict__ dvi, _Float16* __restrict__ agg, int NG) {
  int wave = threadIdx.x >> 6;
  int lane = threadIdx.x & 63;
  int b = blockIdx.x;
  int chunk = b & 7;                // XCD-pinned chunk [0,8)
  int grp = b >> 3;                 // dst group [0, NG)
  int blk = grp * 4 + wave;         // compact dst index
  int d;
  if (ENT) { int bb = blk / 50; d = bb * N_PER_B + 100 + (blk - bb * 50); }
  else d = blk;
  int seg = 2 * d + PASS;
  u32 s0 = __builtin_amdgcn_readfirstlane(off[seg]);
  u32 s1 = __builtin_amdgcn_readfirstlane(off[seg + 1]);
  const h2* xc = (const h2*)xs + chunk * 64 + lane;   // pair column
  h2* outp = (h2*)(agg + (size_t)blk * DCOL) + chunk * 64 + lane;
  h2 part;
  if (PASS) part = *outp;           // prefetch partial early
  h2 c0 = (h2)0.f, c1 = (h2)0.f, c2 = (h2)0.f, c3 = (h2)0.f;
  h2 c4 = (h2)0.f, c5 = (h2)0.f, c6 = (h2)0.f, c7 = (h2)0.f;
  h2 c8 = (h2)0.f, c9 = (h2)0.f, cA = (h2)0.f, cB = (h2)0.f;
  h2 cC = (h2)0.f, cD = (h2)0.f, cE = (h2)0.f, cF = (h2)0.f;
  for (u32 base = s0; base < s1; base += 64) {
    u32 nrem = s1 - base;
    u32 iters = nrem < 64u ? nrem : 64u;
    int sv = srcs[base + (lane < iters ? lane : 0u)];
    u32 j = 0;
    for (; j + 16 <= iters; j += 16) {
      int i0 = __builtin_amdgcn_readlane(sv, j + 0);
      int i1 = __builtin_amdgcn_readlane(sv, j + 1);
      int i2 = __builtin_amdgcn_readlane(sv, j + 2);
      int i3 = __builtin_amdgcn_readlane(sv, j + 3);
      int i4 = __builtin_amdgcn_readlane(sv, j + 4);
      int i5 = __builtin_amdgcn_readlane(sv, j + 5);
      int i6 = __builtin_amdgcn_readlane(sv, j + 6);
      int i7 = __builtin_amdgcn_readlane(sv, j + 7);
      int i8 = __builtin_amdgcn_readlane(sv, j + 8);
      int i9 = __builtin_amdgcn_readlane(sv, j + 9);
      int iA = __builtin_amdgcn_readlane(sv, j + 10);
      int iB = __builtin_amdgcn_readlane(sv, j + 11);
      int iC = __builtin_amdgcn_readlane(sv, j + 12);
      int iD = __builtin_amdgcn_readlane(sv, j + 13);
      int iE = __builtin_amdgcn_readlane(sv, j + 14);
      int iF = __builtin_amdgcn_readlane(sv, j + 15);
      h2 v0 = xc[(size_t)i0 * 512];
      h2 v1 = xc[(size_t)i1 * 512];
      h2 v2 = xc[(size_t)i2 * 512];
      h2 v3 = xc[(size_t)i3 * 512];
      h2 v4 = xc[(size_t)i4 * 512];
      h2 v5 = xc[(size_t)i5 * 512];
      h2 v6 = xc[(size_t)i6 * 512];
      h2 v7 = xc[(size_t)i7 * 512];
      h2 v8 = xc[(size_t)i8 * 512];
      h2 v9 = xc[(size_t)i9 * 512];
      h2 vA = xc[(size_t)iA * 512];
      h2 vB = xc[(size_t)iB * 512];
      h2 vC = xc[(size_t)iC * 512];
      h2 vD = xc[(size_t)iD * 512];
      h2 vE = xc[(size_t)iE * 512];
      h2 vF = xc[(size_t)iF * 512];
      c0 += v0; c1 += v1; c2 += v2; c3 += v3;
      c4 += v4; c5 += v5; c6 += v6; c7 += v7;
      c8 += v8; c9 += v9; cA += vA; cB += vB;
      cC += vC; cD += vD; cE += vE; cF += vF;
    }
    for (; j + 4 <= iters; j += 4) {
      int i0 = __builtin_amdgcn_readlane(sv, j + 0);
      int i1 = __builtin_amdgcn_readlane(sv, j + 1);
      int i2 = __builtin_amdgcn_readlane(sv, j + 2);
      int i3 = __builtin_amdgcn_readlane(sv, j + 3);
      h2 v0 = xc[(size_t)i0 * 512];
      h2 v1 = xc[(size_t)i1 * 512];
      h2 v2 = xc[(size_t)i2 * 512];
      h2 v3 = xc[(size_t)i3 * 512];
      c0 += v0; c1 += v1; c2 += v2; c3 += v3;
    }
    for (; j < iters; ++j) {
      int i0 = __builtin_amdgcn_readlane(sv, j);
      c0 += xc[(size_t)i0 * 512];
    }
  }
  c0 += c8; c1 += c9; c2 += cA; c3 += cB;
  c4 += cC; c5 += cD; c6 += cE; c7 += cF;
  float lo = (((float)c0.x + (float)c1.x) + ((float)c2.x + (float)c3.x)) +
             (((float)c4.x + (float)c5.x) + ((float)c6.x + (float)c7.x));
  float hi = (((float)c0.y + (float)c1.y) + ((float)c2.y + (float)c3.y)) +
             (((float)c4.y + (float)c5.y) + ((float)c6.y + (float)c7.y));
  h2 r;
  if (PASS == 0) {
    r.x = (_Float16)lo;
    r.y = (_Float16)hi;
  } else {
    float wi = dvi[d];
    r.x = (_Float16)((lo + (float)part.x) * wi);
    r.y = (_Float16)((hi + (float)part.y) * wi);
  }
  *outp = r;
}

// ---------------- MFMA GEMM: C = A[M,K] * Bt[N,K]^T (+bias, epilogue) ----------------
// BK=64 via two BK=32 panels per barrier pair (halves barrier-drain stalls;
// LDS addressing identical to the conflict-free BK=32 layout).
// EPI 0: leaky_relu(C+bias)*dvo[row] -> f16 ; EPI 1: C+bias -> f32
// EPI 2: leaky_relu(C+bias) -> f16

template<int EPI>
__global__ __launch_bounds__(256, 3) void gemm_bt(const _Float16* __restrict__ A,
    const _Float16* __restrict__ Bt, const float* __restrict__ bias,
    const float* __restrict__ dvo,
    _Float16* __restrict__ outh, float* __restrict__ outf, int N, int K) {
  __shared__ __align__(16) _Float16 sA[2][128 * 32];
  __shared__ __align__(16) _Float16 sB[2][128 * 32];
  int tid = threadIdx.x;
  int wave = tid >> 6, lane = tid & 63;
  int wm = wave & 1, wn = wave >> 1;
  int lane16 = lane & 15, quad = lane >> 4;
  int m0 = blockIdx.y * 128, n0 = blockIdx.x * 128;
  int srow  = lane >> 2;          // 0..15
  int scolb = (lane & 3) * 16;    // byte offset within 64B row
  const char* aBase = (const char*)(A  + (size_t)(m0 + wave * 32 + srow) * K) + scolb;
  const char* bBase = (const char*)(Bt + (size_t)(n0 + wave * 32 + srow) * K) + scolb;
  const size_t rowSkip = (size_t)16 * K * sizeof(_Float16);
  _Float16* lA0 = &sA[0][(wave * 2 + 0) * 512];
  _Float16* lA1 = &sA[0][(wave * 2 + 1) * 512];
  _Float16* lB0 = &sB[0][(wave * 2 + 0) * 512];
  _Float16* lB1 = &sB[0][(wave * 2 + 1) * 512];
  _Float16* lA0b = &sA[1][(wave * 2 + 0) * 512];
  _Float16* lA1b = &sA[1][(wave * 2 + 1) * 512];
  _Float16* lB0b = &sB[1][(wave * 2 + 0) * 512];
  _Float16* lB1b = &sB[1][(wave * 2 + 1) * 512];

  f32x4 acc[4][4];
  f32x4 zero = {0.f, 0.f, 0.f, 0.f};
#pragma unroll
  for (int i = 0; i < 4; ++i)
#pragma unroll
    for (int j = 0; j < 4; ++j) acc[i][j] = zero;

  for (int k0 = 0; k0 < K; k0 += 64) {
    __syncthreads();
    size_t kb = (size_t)k0 * sizeof(_Float16);
    gload16(aBase + kb,                lA0);
    gload16(aBase + kb + rowSkip,      lA1);
    gload16(bBase + kb,                lB0);
    gload16(bBase + kb + rowSkip,      lB1);
    gload16(aBase + kb + 64,           lA0b);
    gload16(aBase + kb + 64 + rowSkip, lA1b);
    gload16(bBase + kb + 64,           lB0b);
    gload16(bBase + kb + 64 + rowSkip, lB1b);
    __syncthreads();  // drains vmcnt before any wave reads LDS
#pragma unroll
    for (int pnl = 0; pnl < 2; ++pnl) {
      h8 af[4], bq[4];
#pragma unroll
      for (int mt = 0; mt < 4; ++mt)
        af[mt] = *(const h8*)&sA[pnl][(wm * 64 + mt * 16 + lane16) * 32 + quad * 8];
#pragma unroll
      for (int nt = 0; nt < 4; ++nt)
        bq[nt] = *(const h8*)&sB[pnl][(wn * 64 + nt * 16 + lane16) * 32 + quad * 8];
#pragma unroll
      for (int mt = 0; mt < 4; ++mt)
#pragma unroll
        for (int nt = 0; nt < 4; ++nt)
          acc[mt][nt] = __builtin_amdgcn_mfma_f32_16x16x32_f16(af[mt], bq[nt], acc[mt][nt], 0, 0, 0);
    }
  }

#pragma unroll
  for (int nt = 0; nt < 4; ++nt) {
    int n = n0 + wn * 64 + nt * 16 + lane16;
    float bv = bias[n];
#pragma unroll
    for (int mt = 0; mt < 4; ++mt) {
      int mb = m0 + wm * 64 + mt * 16 + quad * 4;  // C/D: row = quad*4+i, col = lane16
#pragma unroll
      for (int i = 0; i < 4; ++i) {
        float v = acc[mt][nt][i] + bv;
        if (EPI == 0) {
          v = (v > 0.f) ? v : 0.01f * v;
          v *= dvo[mb + i];
          outh[(size_t)(mb + i) * N + n] = (_Float16)v;
        } else if (EPI == 2) {
          v = (v > 0.f) ? v : 0.01f * v;
          outh[(size_t)(mb + i) * N + n] = (_Float16)v;
        } else {
          outf[(size_t)(mb + i) * N + n] = v;
        }
      }
    }
  }
}

// ---------------- launch ----------------

extern "C" void kernel_launch(void* const* d_in, const int* in_sizes, int n_in,
                              void* d_out, int out_size, void* d_ws, size_t ws_size,
                              hipStream_t stream) {
  const float* mh  = (const float*)d_in[0];
  const float* eh  = (const float*)d_in[1];
  const float* sh  = (const float*)d_in[2];
  const int*   es  = (const int*)d_in[3];
  const int*   ed  = (const int*)d_in[4];
  const float* te  = (const float*)d_in[5];
  const float* lns = (const float*)d_in[6];
  const float* lnb = (const float*)d_in[7];
  const float* gw  = (const float*)d_in[8];   // [3][1024][1024]
  const float* gb  = (const float*)d_in[9];   // [3][1024]
  const float* fw  = (const float*)d_in[10];  // [1024][768]
  const float* fb  = (const float*)d_in[11];  // [768]
  float* out = (float*)d_out;                 // [128*50*768] f32
  int nE = in_sizes[3];

  char* p = (char*)d_ws;
  auto alloc = [&](size_t bytes) -> void* {
    void* r = (void*)p;
    p += (bytes + 255) & ~(size_t)255;
    return r;
  };
  _Float16* xbuf = (_Float16*)alloc((size_t)NN * DCOL * 2);
  _Float16* agg  = (_Float16*)alloc((size_t)NN * DCOL * 2);
  _Float16* wt   = (_Float16*)alloc((size_t)3 * 1024 * 1024 * 2);
  _Float16* wtfc = (_Float16*)alloc((size_t)768 * 1024 * 2);
  u32* deg_out = (u32*)alloc((size_t)NN * 4);       // contiguous with next two
  u32* din2    = (u32*)alloc((size_t)2 * NN * 4);   // (d, src-half) buckets
  u32* cursor  = (u32*)alloc((size_t)2 * NN * 4);
  u32* csr_off = (u32*)alloc((size_t)(2 * NN + 1) * 4);
  float* dvo = (float*)alloc((size_t)NN * 4);
  float* dvi = (float*)alloc((size_t)NN * 4);
  int* csr_src = (int*)alloc((size_t)nE * 4);

  hipMemsetAsync(deg_out, 0, (size_t)5 * NN * 4, stream);  // deg_out, din2, cursor

  int eb = (nE + 255) / 256;
  degree_k<<<eb, 256, 0, stream>>>(es, ed, deg_out, din2, nE);
  dinv_k<<<(NN + 255) / 256, 256, 0, stream>>>(deg_out, din2, dvo, dvi);
  scan_k<<<1, 1024, 0, stream>>>(din2, csr_off, 2 * NN);
  scatter_k<<<eb, 256, 0, stream>>>(es, ed, csr_off, cursor, csr_src, nE);
  ln_k<<<NN, 256, 0, stream>>>(mh, eh, sh, te, lns, lnb, dvo, xbuf);
  transpose_k<<<dim3(32, 32), 256, 0, stream>>>(gw + 0 * 1048576, wt + 0 * 1048576, 1024, 1024);
  transpose_k<<<dim3(32, 32), 256, 0, stream>>>(gw + 1 * 1048576, wt + 1 * 1048576, 1024, 1024);
  transpose_k<<<dim3(32, 32), 256, 0, stream>>>(gw + 2 * 1048576, wt + 2 * 1048576, 1024, 1024);
  transpose_k<<<dim3(24, 32), 256, 0, stream>>>(fw, wtfc, 1024, 768);

  // layer 0  (xbuf is pre-scaled by dvo)
  aggregate_k<0, 0><<<8 * 5600, 256, 0, stream>>>(xbuf, csr_off, csr_src, dvi, agg, 5600);
  aggregate_k<0, 1><<<8 * 5600, 256, 0, stream>>>(xbuf, csr_off, csr_src, dvi, agg, 5600);
  gemm_bt<0><<<dim3(8, 175), 256, 0, stream>>>(agg, wt + 0 * 1048576, gb + 0,    dvo, xbuf, nullptr, 1024, 1024);
  // layer 1
  aggregate_k<0, 0><<<8 * 5600, 256, 0, stream>>>(xbuf, csr_off, csr_src, dvi, agg, 5600);
  aggregate_k<0, 1><<<8 * 5600, 256, 0, stream>>>(xbuf, csr_off, csr_src, dvi, agg, 5600);
  gemm_bt<0><<<dim3(8, 175), 256, 0, stream>>>(agg, wt + 1 * 1048576, gb + 1024, dvo, xbuf, nullptr, 1024, 1024);
  // layer 2: only entity dst rows consumed downstream -> compact 6400 rows, unscaled out
  aggregate_k<1, 0><<<8 * 1600, 256, 0, stream>>>(xbuf, csr_off, csr_src, dvi, agg, 1600);
  aggregate_k<1, 1><<<8 * 1600, 256, 0, stream>>>(xbuf, csr_off, csr_src, dvi, agg, 1600);
  gemm_bt<2><<<dim3(8, 50), 256, 0, stream>>>(agg, wt + 2 * 1048576, gb + 2048, nullptr, xbuf, nullptr, 1024, 1024);
  // FC on compact entity rows -> d_out [6400][768] f32
  gemm_bt<1><<<dim3(6, 50), 256, 0, stream>>>(xbuf, wtfc, fb, nullptr, nullptr, out, 768, 1024);
}

// Round 8
// 664.594 us; speedup vs baseline: 1.1925x; 1.1925x over previous
//
#include <hip/hip_runtime.h>
#include <cstdint>

using u16 = unsigned short;
using u32 = unsigned int;

typedef _Float16 h8 __attribute__((ext_vector_type(8)));
typedef _Float16 h4 __attribute__((ext_vector_type(4)));
typedef _Float16 h2 __attribute__((ext_vector_type(2)));
typedef float f32x4 __attribute__((ext_vector_type(4)));

#define N_PER_B 175
#define NN 22400
#define DCOL 1024

// async global->LDS, 16B per lane; LDS dst is wave-uniform base + lane*16
__device__ __forceinline__ void gload16(const void* g, void* l) {
  void* gnc = const_cast<void*>(g);
  __builtin_amdgcn_global_load_lds(
      (__attribute__((address_space(1))) unsigned int*)gnc,
      (__attribute__((address_space(3))) unsigned int*)l, 16, 0, 0);
}

// ---------------- degree / CSR build ----------------

__global__ void degree_k(const int* __restrict__ es, const int* __restrict__ ed,
                         u32* __restrict__ dout, u32* __restrict__ din, int nE) {
  int e = blockIdx.x * 256 + threadIdx.x;
  if (e < nE) {
    atomicAdd(&dout[es[e]], 1u);
    atomicAdd(&din[ed[e]], 1u);
  }
}

__global__ void dinv_k(const u32* __restrict__ dout, const u32* __restrict__ din,
                       float* __restrict__ vo, float* __restrict__ vi) {
  int i = blockIdx.x * 256 + threadIdx.x;
  if (i < NN) {
    u32 a = dout[i]; if (a == 0u) a = 1u;
    u32 b = din[i];  if (b == 0u) b = 1u;
    vo[i] = rsqrtf((float)a);
    vi[i] = rsqrtf((float)b);
  }
}

// single-block scan, wave-shuffle based: 2 barriers per 1024-chunk
__global__ __launch_bounds__(1024) void scan_k(const u32* __restrict__ deg,
                                               u32* __restrict__ off, int n) {
  __shared__ u32 wsum[16];
  __shared__ u32 carry_s;
  int tid = threadIdx.x;
  int lane = tid & 63, w = tid >> 6;
  if (tid == 0) carry_s = 0u;
  __syncthreads();
  for (int base = 0; base < n; base += 1024) {
    u32 cb = carry_s;
    int i = base + tid;
    u32 v = (i < n) ? deg[i] : 0u;
    u32 x = v;
#pragma unroll
    for (int o = 1; o < 64; o <<= 1) {
      u32 t = __shfl_up(x, o);
      if (lane >= o) x += t;
    }
    if (lane == 63) wsum[w] = x;
    __syncthreads();
    u32 woff = 0;
#pragma unroll
    for (int j = 0; j < 16; ++j) { u32 s = wsum[j]; if (j < w) woff += s; }
    u32 incl = cb + woff + x;
    if (i < n) off[i] = incl - v;          // exclusive
    if (tid == 1023) carry_s = incl;
    __syncthreads();
  }
  if (tid == 0) off[n] = carry_s;
}

__global__ void scatter_k(const int* __restrict__ es, const int* __restrict__ ed,
                          const u32* __restrict__ off, u32* __restrict__ cur,
                          int* __restrict__ csr, int nE) {
  int e = blockIdx.x * 256 + threadIdx.x;
  if (e < nE) {
    int d = ed[e];
    u32 p = atomicAdd(&cur[d], 1u);
    csr[off[d] + p] = es[e];
  }
}

// ---------------- concat + layernorm (+ *dvo) -> fp16 node matrix ----------------

__global__ __launch_bounds__(256) void ln_k(const float* __restrict__ mh,
    const float* __restrict__ eh, const float* __restrict__ sh,
    const float* __restrict__ te, const float* __restrict__ sc,
    const float* __restrict__ bi, const float* __restrict__ dvo,
    _Float16* __restrict__ x0) {
  int node = blockIdx.x;
  int b = node / N_PER_B;
  int p = node - b * N_PER_B;
  const float* row;
  int t;
  if (p < 100)      { row = mh + ((size_t)b * 100 + p) * 768;        t = 0; }
  else if (p < 150) { row = eh + ((size_t)b * 50 + (p - 100)) * 768; t = 1; }
  else              { row = sh + ((size_t)b * 25 + (p - 150)) * 768; t = 2; }
  int tid = threadIdx.x;
  const float* lp = (tid < 192) ? (row + tid * 4) : (te + t * 256 + (tid - 192) * 4);
  float4 v = *(const float4*)lp;
  float s = v.x + v.y + v.z + v.w;
  float q = v.x * v.x + v.y * v.y + v.z * v.z + v.w * v.w;
#pragma unroll
  for (int o = 32; o > 0; o >>= 1) { s += __shfl_down(s, o); q += __shfl_down(q, o); }
  __shared__ float red[8];
  int w = tid >> 6;
  if ((tid & 63) == 0) { red[w] = s; red[4 + w] = q; }
  __syncthreads();
  float ts = red[0] + red[1] + red[2] + red[3];
  float tq = red[4] + red[5] + red[6] + red[7];
  float mu = ts * (1.0f / 1024.0f);
  float var = tq * (1.0f / 1024.0f) - mu * mu;
  float r = rsqrtf(var + 1e-5f);
  float scale_o = dvo[node];
  int c = tid * 4;
  float4 g  = *(const float4*)(sc + c);
  float4 hb = *(const float4*)(bi + c);
  h4 o;
  o.x = (_Float16)(((v.x - mu) * r * g.x + hb.x) * scale_o);
  o.y = (_Float16)(((v.y - mu) * r * g.y + hb.y) * scale_o);
  o.z = (_Float16)(((v.z - mu) * r * g.z + hb.z) * scale_o);
  o.w = (_Float16)(((v.w - mu) * r * g.w + hb.w) * scale_o);
  *(h4*)(x0 + (size_t)node * DCOL + c) = o;
}

// ---------------- weight transpose fp32 [K][N] -> fp16 [N][K] ----------------

__global__ __launch_bounds__(256) void transpose_k(const float* __restrict__ W,
    _Float16* __restrict__ Wt, int K, int N) {
  __shared__ float tile[32][33];
  int n0 = blockIdx.x * 32, k0 = blockIdx.y * 32;
  int tx = threadIdx.x & 31, ty = threadIdx.x >> 5;  // 32 x 8
#pragma unroll
  for (int i = 0; i < 32; i += 8)
    tile[ty + i][tx] = W[(size_t)(k0 + ty + i) * N + n0 + tx];
  __syncthreads();
#pragma unroll
  for (int i = 0; i < 32; i += 8)
    Wt[(size_t)(n0 + ty + i) * K + k0 + tx] = (_Float16)tile[tx][ty + i];
}

// ---------------- CSR aggregation (single pass, R6 form) ----------------
// xs is pre-scaled by dvo. One wave per (dst, 128-col chunk); lane = col pair.
// agg[d] = dvi[d] * sum_src xs[src]
// 64 edge indices per vector load, readlane extraction, 16-way gather MLP,
// 8 chunks <-> 8 XCDs via blockIdx&7.

template<int ENT>
__global__ __launch_bounds__(256) void aggregate_k(const _Float16* __restrict__ xs,
    const u32* __restrict__ off, const int* __restrict__ srcs,
    const float* __restrict__ dvi, _Float16* __restrict__ out, int NG) {
  int wave = threadIdx.x >> 6;
  int lane = threadIdx.x & 63;
  int b = blockIdx.x;
  int chunk = b & 7;                // XCD-pinned chunk [0,8)
  int grp = b >> 3;                 // dst group [0, NG)
  int blk = grp * 4 + wave;         // compact dst index
  int d;
  if (ENT) { int bb = blk / 50; d = bb * N_PER_B + 100 + (blk - bb * 50); }
  else d = blk;
  u32 s0 = __builtin_amdgcn_readfirstlane(off[d]);
  u32 s1 = __builtin_amdgcn_readfirstlane(off[d + 1]);
  const h2* xc = (const h2*)xs + chunk * 64 + lane;   // pair column
  h2 c0 = (h2)0.f, c1 = (h2)0.f, c2 = (h2)0.f, c3 = (h2)0.f;
  h2 c4 = (h2)0.f, c5 = (h2)0.f, c6 = (h2)0.f, c7 = (h2)0.f;
  h2 c8 = (h2)0.f, c9 = (h2)0.f, cA = (h2)0.f, cB = (h2)0.f;
  h2 cC = (h2)0.f, cD = (h2)0.f, cE = (h2)0.f, cF = (h2)0.f;
  for (u32 base = s0; base < s1; base += 64) {
    u32 nrem = s1 - base;
    u32 iters = nrem < 64u ? nrem : 64u;
    int sv = srcs[base + (lane < iters ? lane : 0u)];
    u32 j = 0;
    for (; j + 16 <= iters; j += 16) {
      int i0 = __builtin_amdgcn_readlane(sv, j + 0);
      int i1 = __builtin_amdgcn_readlane(sv, j + 1);
      int i2 = __builtin_amdgcn_readlane(sv, j + 2);
      int i3 = __builtin_amdgcn_readlane(sv, j + 3);
      int i4 = __builtin_amdgcn_readlane(sv, j + 4);
      int i5 = __builtin_amdgcn_readlane(sv, j + 5);
      int i6 = __builtin_amdgcn_readlane(sv, j + 6);
      int i7 = __builtin_amdgcn_readlane(sv, j + 7);
      int i8 = __builtin_amdgcn_readlane(sv, j + 8);
      int i9 = __builtin_amdgcn_readlane(sv, j + 9);
      int iA = __builtin_amdgcn_readlane(sv, j + 10);
      int iB = __builtin_amdgcn_readlane(sv, j + 11);
      int iC = __builtin_amdgcn_readlane(sv, j + 12);
      int iD = __builtin_amdgcn_readlane(sv, j + 13);
      int iE = __builtin_amdgcn_readlane(sv, j + 14);
      int iF = __builtin_amdgcn_readlane(sv, j + 15);
      h2 v0 = xc[(size_t)i0 * 512];
      h2 v1 = xc[(size_t)i1 * 512];
      h2 v2 = xc[(size_t)i2 * 512];
      h2 v3 = xc[(size_t)i3 * 512];
      h2 v4 = xc[(size_t)i4 * 512];
      h2 v5 = xc[(size_t)i5 * 512];
      h2 v6 = xc[(size_t)i6 * 512];
      h2 v7 = xc[(size_t)i7 * 512];
      h2 v8 = xc[(size_t)i8 * 512];
      h2 v9 = xc[(size_t)i9 * 512];
      h2 vA = xc[(size_t)iA * 512];
      h2 vB = xc[(size_t)iB * 512];
      h2 vC = xc[(size_t)iC * 512];
      h2 vD = xc[(size_t)iD * 512];
      h2 vE = xc[(size_t)iE * 512];
      h2 vF = xc[(size_t)iF * 512];
      c0 += v0; c1 += v1; c2 += v2; c3 += v3;
      c4 += v4; c5 += v5; c6 += v6; c7 += v7;
      c8 += v8; c9 += v9; cA += vA; cB += vB;
      cC += vC; cD += vD; cE += vE; cF += vF;
    }
    for (; j + 4 <= iters; j += 4) {
      int i0 = __builtin_amdgcn_readlane(sv, j + 0);
      int i1 = __builtin_amdgcn_readlane(sv, j + 1);
      int i2 = __builtin_amdgcn_readlane(sv, j + 2);
      int i3 = __builtin_amdgcn_readlane(sv, j + 3);
      h2 v0 = xc[(size_t)i0 * 512];
      h2 v1 = xc[(size_t)i1 * 512];
      h2 v2 = xc[(size_t)i2 * 512];
      h2 v3 = xc[(size_t)i3 * 512];
      c0 += v0; c1 += v1; c2 += v2; c3 += v3;
    }
    for (; j < iters; ++j) {
      int i0 = __builtin_amdgcn_readlane(sv, j);
      c0 += xc[(size_t)i0 * 512];
    }
  }
  c0 += c8; c1 += c9; c2 += cA; c3 += cB;
  c4 += cC; c5 += cD; c6 += cE; c7 += cF;
  float wi = dvi[d];
  float lo = (((float)c0.x + (float)c1.x) + ((float)c2.x + (float)c3.x)) +
             (((float)c4.x + (float)c5.x) + ((float)c6.x + (float)c7.x));
  float hi = (((float)c0.y + (float)c1.y) + ((float)c2.y + (float)c3.y)) +
             (((float)c4.y + (float)c5.y) + ((float)c6.y + (float)c7.y));
  h2 r;
  r.x = (_Float16)(lo * wi);
  r.y = (_Float16)(hi * wi);
  *((h2*)(out + (size_t)blk * DCOL) + chunk * 64 + lane) = r;
}

// ---------------- MFMA GEMM: C = A[M,K] * Bt[N,K]^T (+bias, epilogue) ----------------
// XCD-aware 1D grid: xcd=id&7 owns a contiguous band of m-tiles and runs all
// n-tiles of an m-row back-to-back on that XCD -> A-tile fetched into that
// XCD's L2 once, B resident. (Fixes 183MB -> ~65MB L2 fill.)
// BK=64 via two BK=32 panels per barrier pair.
// EPI 0: leaky_relu(C+bias)*dvo[row]->f16 ; EPI 1: C+bias->f32 ; EPI 2: lrelu->f16

template<int EPI>
__global__ __launch_bounds__(256, 3) void gemm_bt(const _Float16* __restrict__ A,
    const _Float16* __restrict__ Bt, const float* __restrict__ bias,
    const float* __restrict__ dvo,
    _Float16* __restrict__ outh, float* __restrict__ outf,
    int N, int K, int Mtiles, int NBN) {
  int id = blockIdx.x;
  int xcd = id & 7;
  int rest = id >> 3;
  int ntile = rest % NBN;
  int mloc = rest / NBN;
  int mpx = (Mtiles + 7) >> 3;           // m-tiles per XCD band
  int mtile = xcd * mpx + mloc;
  if (mtile >= Mtiles) return;           // block-uniform, before any barrier
  int m0 = mtile * 128, n0 = ntile * 128;

  __shared__ __align__(16) _Float16 sA[2][128 * 32];
  __shared__ __align__(16) _Float16 sB[2][128 * 32];
  int tid = threadIdx.x;
  int wave = tid >> 6, lane = tid & 63;
  int wm = wave & 1, wn = wave >> 1;
  int lane16 = lane & 15, quad = lane >> 4;
  int srow  = lane >> 2;          // 0..15
  int scolb = (lane & 3) * 16;    // byte offset within 64B row
  const char* aBase = (const char*)(A  + (size_t)(m0 + wave * 32 + srow) * K) + scolb;
  const char* bBase = (const char*)(Bt + (size_t)(n0 + wave * 32 + srow) * K) + scolb;
  const size_t rowSkip = (size_t)16 * K * sizeof(_Float16);
  _Float16* lA0 = &sA[0][(wave * 2 + 0) * 512];
  _Float16* lA1 = &sA[0][(wave * 2 + 1) * 512];
  _Float16* lB0 = &sB[0][(wave * 2 + 0) * 512];
  _Float16* lB1 = &sB[0][(wave * 2 + 1) * 512];
  _Float16* lA0b = &sA[1][(wave * 2 + 0) * 512];
  _Float16* lA1b = &sA[1][(wave * 2 + 1) * 512];
  _Float16* lB0b = &sB[1][(wave * 2 + 0) * 512];
  _Float16* lB1b = &sB[1][(wave * 2 + 1) * 512];

  f32x4 acc[4][4];
  f32x4 zero = {0.f, 0.f, 0.f, 0.f};
#pragma unroll
  for (int i = 0; i < 4; ++i)
#pragma unroll
    for (int j = 0; j < 4; ++j) acc[i][j] = zero;

  for (int k0 = 0; k0 < K; k0 += 64) {
    __syncthreads();
    size_t kb = (size_t)k0 * sizeof(_Float16);
    gload16(aBase + kb,                lA0);
    gload16(aBase + kb + rowSkip,      lA1);
    gload16(bBase + kb,                lB0);
    gload16(bBase + kb + rowSkip,      lB1);
    gload16(aBase + kb + 64,           lA0b);
    gload16(aBase + kb + 64 + rowSkip, lA1b);
    gload16(bBase + kb + 64,           lB0b);
    gload16(bBase + kb + 64 + rowSkip, lB1b);
    __syncthreads();  // drains vmcnt before any wave reads LDS
#pragma unroll
    for (int pnl = 0; pnl < 2; ++pnl) {
      h8 af[4], bq[4];
#pragma unroll
      for (int mt = 0; mt < 4; ++mt)
        af[mt] = *(const h8*)&sA[pnl][(wm * 64 + mt * 16 + lane16) * 32 + quad * 8];
#pragma unroll
      for (int nt = 0; nt < 4; ++nt)
        bq[nt] = *(const h8*)&sB[pnl][(wn * 64 + nt * 16 + lane16) * 32 + quad * 8];
#pragma unroll
      for (int mt = 0; mt < 4; ++mt)
#pragma unroll
        for (int nt = 0; nt < 4; ++nt)
          acc[mt][nt] = __builtin_amdgcn_mfma_f32_16x16x32_f16(af[mt], bq[nt], acc[mt][nt], 0, 0, 0);
    }
  }

#pragma unroll
  for (int nt = 0; nt < 4; ++nt) {
    int n = n0 + wn * 64 + nt * 16 + lane16;
    float bv = bias[n];
#pragma unroll
    for (int mt = 0; mt < 4; ++mt) {
      int mb = m0 + wm * 64 + mt * 16 + quad * 4;  // C/D: row = quad*4+i, col = lane16
#pragma unroll
      for (int i = 0; i < 4; ++i) {
        float v = acc[mt][nt][i] + bv;
        if (EPI == 0) {
          v = (v > 0.f) ? v : 0.01f * v;
          v *= dvo[mb + i];
          outh[(size_t)(mb + i) * N + n] = (_Float16)v;
        } else if (EPI == 2) {
          v = (v > 0.f) ? v : 0.01f * v;
          outh[(size_t)(mb + i) * N + n] = (_Float16)v;
        } else {
          outf[(size_t)(mb + i) * N + n] = v;
        }
      }
    }
  }
}

// ---------------- launch ----------------

extern "C" void kernel_launch(void* const* d_in, const int* in_sizes, int n_in,
                              void* d_out, int out_size, void* d_ws, size_t ws_size,
                              hipStream_t stream) {
  const float* mh  = (const float*)d_in[0];
  const float* eh  = (const float*)d_in[1];
  const float* sh  = (const float*)d_in[2];
  const int*   es  = (const int*)d_in[3];
  const int*   ed  = (const int*)d_in[4];
  const float* te  = (const float*)d_in[5];
  const float* lns = (const float*)d_in[6];
  const float* lnb = (const float*)d_in[7];
  const float* gw  = (const float*)d_in[8];   // [3][1024][1024]
  const float* gb  = (const float*)d_in[9];   // [3][1024]
  const float* fw  = (const float*)d_in[10];  // [1024][768]
  const float* fb  = (const float*)d_in[11];  // [768]
  float* out = (float*)d_out;                 // [128*50*768] f32
  int nE = in_sizes[3];

  char* p = (char*)d_ws;
  auto alloc = [&](size_t bytes) -> void* {
    void* r = (void*)p;
    p += (bytes + 255) & ~(size_t)255;
    return r;
  };
  _Float16* xbuf = (_Float16*)alloc((size_t)NN * DCOL * 2);
  _Float16* agg  = (_Float16*)alloc((size_t)NN * DCOL * 2);
  _Float16* wt   = (_Float16*)alloc((size_t)3 * 1024 * 1024 * 2);
  _Float16* wtfc = (_Float16*)alloc((size_t)768 * 1024 * 2);
  u32* deg_out = (u32*)alloc((size_t)NN * 4);   // these three stay contiguous
  u32* deg_in  = (u32*)alloc((size_t)NN * 4);
  u32* cursor  = (u32*)alloc((size_t)NN * 4);
  u32* csr_off = (u32*)alloc((size_t)(NN + 1) * 4);
  float* dvo = (float*)alloc((size_t)NN * 4);
  float* dvi = (float*)alloc((size_t)NN * 4);
  int* csr_src = (int*)alloc((size_t)nE * 4);

  hipMemsetAsync(deg_out, 0, (size_t)3 * NN * 4, stream);  // deg_out, deg_in, cursor

  int eb = (nE + 255) / 256;
  degree_k<<<eb, 256, 0, stream>>>(es, ed, deg_out, deg_in, nE);
  dinv_k<<<(NN + 255) / 256, 256, 0, stream>>>(deg_out, deg_in, dvo, dvi);
  scan_k<<<1, 1024, 0, stream>>>(deg_in, csr_off, NN);
  scatter_k<<<eb, 256, 0, stream>>>(es, ed, csr_off, cursor, csr_src, nE);
  ln_k<<<NN, 256, 0, stream>>>(mh, eh, sh, te, lns, lnb, dvo, xbuf);
  transpose_k<<<dim3(32, 32), 256, 0, stream>>>(gw + 0 * 1048576, wt + 0 * 1048576, 1024, 1024);
  transpose_k<<<dim3(32, 32), 256, 0, stream>>>(gw + 1 * 1048576, wt + 1 * 1048576, 1024, 1024);
  transpose_k<<<dim3(32, 32), 256, 0, stream>>>(gw + 2 * 1048576, wt + 2 * 1048576, 1024, 1024);
  transpose_k<<<dim3(24, 32), 256, 0, stream>>>(fw, wtfc, 1024, 768);

  // Big GEMMs: Mtiles=175 -> mpx=22 -> grid 8*22*8=1408 (8 tail blocks no-op)
  // L2 GEMM:  Mtiles=50  -> mpx=7  -> grid 8*7*8=448
  // FC GEMM:  Mtiles=50, NBN=6     -> grid 8*7*6=336

  // layer 0  (xbuf is pre-scaled by dvo)
  aggregate_k<0><<<8 * 5600, 256, 0, stream>>>(xbuf, csr_off, csr_src, dvi, agg, 5600);
  gemm_bt<0><<<1408, 256, 0, stream>>>(agg, wt + 0 * 1048576, gb + 0,    dvo, xbuf, nullptr, 1024, 1024, 175, 8);
  // layer 1
  aggregate_k<0><<<8 * 5600, 256, 0, stream>>>(xbuf, csr_off, csr_src, dvi, agg, 5600);
  gemm_bt<0><<<1408, 256, 0, stream>>>(agg, wt + 1 * 1048576, gb + 1024, dvo, xbuf, nullptr, 1024, 1024, 175, 8);
  // layer 2: only entity dst rows consumed downstream -> compact 6400 rows, unscaled out
  aggregate_k<1><<<8 * 1600, 256, 0, stream>>>(xbuf, csr_off, csr_src, dvi, agg, 1600);
  gemm_bt<2><<<448, 256, 0, stream>>>(agg, wt + 2 * 1048576, gb + 2048, nullptr, xbuf, nullptr, 1024, 1024, 50, 8);
  // FC on compact entity rows -> d_out [6400][768] f32
  gemm_bt<1><<<336, 256, 0, stream>>>(xbuf, wtfc, fb, nullptr, nullptr, out, 768, 1024, 50, 6);
}